// Round 12
// baseline (301.943 us; speedup 1.0000x reference)
//
#include <hip/hip_runtime.h>
#include <hip/hip_bf16.h>

typedef __attribute__((ext_vector_type(8))) __bf16 bf16x8;
typedef __attribute__((ext_vector_type(4))) float f32x4;
typedef unsigned short u16;
typedef unsigned int u32;

#define DMODEL 1024
#define SLEN   2048
#define NPROJ  11264
#define NFUSE  5120
#define MROWS  4096

__device__ __forceinline__ float b2f(u16 u){ u32 v=((u32)u)<<16; float f; __builtin_memcpy(&f,&v,4); return f; }
__device__ __forceinline__ u16 f2b(float f){ u32 u; __builtin_memcpy(&u,&f,4); u32 r=u+0x7fffu+((u>>16)&1u); return (u16)(r>>16); }
__device__ __forceinline__ float fexp2(float x){ return __builtin_amdgcn_exp2f(x); }

__device__ __forceinline__ void gload16(const void* g, void* l){
  __builtin_amdgcn_global_load_lds((__attribute__((address_space(1))) u32*)g,
                                   (__attribute__((address_space(3))) u32*)l, 16, 0, 0);
}

// ---------------- fused prep: 3 weight transposes + rope table + cond, one launch ----------------
__global__ __launch_bounds__(256) void k_prep(const float* __restrict__ w_in,
                                              const float* __restrict__ w_attn,
                                              const float* __restrict__ w_ff,
                                              const float* __restrict__ te,
                                              const float* __restrict__ cond_w,
                                              const float* __restrict__ cond_b,
                                              u16* __restrict__ w_inT,
                                              u16* __restrict__ w_fusedT,
                                              float* __restrict__ ropetab,
                                              float* __restrict__ cond){
  __shared__ float tile[32][33];
  __shared__ float sl[DMODEL];
  int bid = blockIdx.x;
  if (bid >= 16384){
    int xb = bid - 16384;
    if (xb < 128){
      int idx = xb*256 + threadIdx.x;
      int s = idx >> 4, i = idx & 15;
      float inv = powf(10000.f, -(float)i/16.f);
      float f = (float)s * inv;
      ropetab[s*32 + i]      = cosf(f);
      ropetab[s*32 + 16 + i] = sinf(f);
    } else {
      int cb2 = xb - 128;
      int b = cb2>>3, t = threadIdx.x;
      for (int i=t;i<DMODEL;i+=256){ float x = te[b*DMODEL+i]; sl[i] = x/(1.f+expf(-x)); }
      __syncthreads();
      int n = (cb2&7)*256 + t;
      float acc = 0.f;
      for (int k=0;k<DMODEL;k++) acc += sl[k]*cond_w[(size_t)k*2048 + n];
      cond[b*2048+n] = acc + cond_b[n];
    }
    return;
  }
  const float* src; u16* dst; int N, ldd, coloff, nx, remap, tix;
  if (bid < 11264){ tix=bid;       nx=352; src=w_in;   N=NPROJ;  dst=w_inT;    ldd=DMODEL; coloff=0;    remap=1; }
  else if (bid < 12288){ tix=bid-11264; nx=32; src=w_attn; N=DMODEL; dst=w_fusedT; ldd=NFUSE; coloff=0;    remap=0; }
  else {            tix=bid-12288; nx=32;  src=w_ff;   N=DMODEL; dst=w_fusedT; ldd=NFUSE;  coloff=1024; remap=0; }
  int n0 = (tix%nx)*32, k0 = (tix/nx)*32;
  int tx = threadIdx.x & 31, ty = threadIdx.x >> 5;
  int srccol;
  if (remap && (n0 + tx) >= 3072){
    int c = n0 + tx - 3072;
    int q = c >> 5, o = c & 31;
    srccol = (o < 16) ? (3072 + 16*q + o) : (7168 + 16*q + (o-16));
  } else srccol = n0 + tx;
  #pragma unroll
  for (int r=0;r<4;r++)
    tile[ty*4+r][tx] = src[(size_t)(k0+ty*4+r)*N + srccol];
  __syncthreads();
  #pragma unroll
  for (int r=0;r<4;r++){
    int n = ty*4+r;
    dst[(size_t)(n0+n)*ldd + coloff + k0 + tx] = f2b(tile[tx][n]);
  }
}

// ---------------- LayerNorm + modulation -> units bf16 ----------------
__global__ __launch_bounds__(256) void k_ln(const float* __restrict__ x, const float* __restrict__ lw,
                                            const float* __restrict__ lb, const float* __restrict__ cond,
                                            u16* __restrict__ units){
  int row = blockIdx.x; int b = row >> 11;
  int t = threadIdx.x;
  const float4 v = *(const float4*)(x + (size_t)row*DMODEL + t*4);
  float s = v.x+v.y+v.z+v.w;
  float q = v.x*v.x+v.y*v.y+v.z*v.z+v.w*v.w;
  #pragma unroll
  for (int off=32; off; off>>=1){ s += __shfl_xor(s,off); q += __shfl_xor(q,off); }
  __shared__ float red[8];
  int w = t>>6, l = t&63;
  if (l==0){ red[w]=s; red[4+w]=q; }
  __syncthreads();
  float S = red[0]+red[1]+red[2]+red[3];
  float Q = red[4]+red[5]+red[6]+red[7];
  float mu = S*(1.f/1024.f);
  float var = Q*(1.f/1024.f) - mu*mu;
  float rstd = rsqrtf(var + 1e-5f);
  int c0 = t*4;
  u16 o[4];
  const float* vf = (const float*)&v;
  #pragma unroll
  for (int i=0;i<4;i++){
    int c = c0+i;
    float nrm = (vf[i]-mu)*rstd*lw[c] + lb[c];
    float outv = (1.f + cond[b*2048 + c])*nrm + cond[b*2048 + 1024 + c];
    o[i] = f2b(outv);
  }
  u32 p0 = (u32)o[0] | ((u32)o[1]<<16);
  u32 p1 = (u32)o[2] | ((u32)o[3]<<16);
  uint2 pk; pk.x = p0; pk.y = p1;
  *(uint2*)(units + (size_t)row*DMODEL + c0) = pk;
}

// ================= pipelined GEMM: counted-vmcnt, raw barriers, NBUF LDS buffers =================
// COLUMN-major XCD decode (co-resident blocks share a B panel -> L2-resident).
// EPI 0: proj epilogue (rope/headsplit/vT-direct/ff-gate). EPI 1: split-K bf16 partials.
template<int BM,int BN,int WM,int WN,int NBUF,int MINW,int EPI>
__global__ __launch_bounds__(WM*WN*64, MINW) void k_gemm_pipe(
    const u16* __restrict__ A, const u16* __restrict__ Bt, int K, int lda, int ldb,
    const float* __restrict__ tab, u16* __restrict__ qh, u16* __restrict__ kh,
    u16* __restrict__ vt, u16* __restrict__ afinal, u16* __restrict__ pb)
{
  constexpr int THREADS = WM*WN*64;
  constexpr int MR = BM/WM/16, NR = BN/WN/16;
  constexpr int BUFE = (BM+BN)*32;
  __shared__ __attribute__((aligned(16))) u16 lds[NBUF*BUFE];
  int t = threadIdx.x, w = t>>6, l = t&63;
  int wr = w/WN, wc = w%WN;
  int lane16 = l&15, lg = l>>4;

  int nbx = gridDim.x, nby = gridDim.y;
  int wg = blockIdx.y*nbx + blockIdx.x;
  int nwg = nbx*nby;
  int cpx = nwg>>3;
  int swz = (wg&7)*cpx + (wg>>3);
  int bx = swz / nby, by = swz - bx*nby;   // column-major: co-resident share B panel

  size_t m0 = (size_t)by*BM, n0 = (size_t)bx*BN;
  int koff = (EPI==1) ? blockIdx.z*2560 : 0;
  const u16* Ag = A + m0*lda + koff;
  const u16* Bg = Bt + n0*ldb + koff;

  f32x4 zero = {0.f,0.f,0.f,0.f};
  f32x4 acc[MR][NR];
  #pragma unroll
  for (int i=0;i<MR;i++)
    #pragma unroll
    for (int j=0;j<NR;j++) acc[i][j] = zero;

  const int ntiles = K/32;

  auto STAGE = [&](int tt, int buf){
    int k0 = tt*32;
    char* Ad = (char*)lds + (size_t)buf*(BUFE*2);
    char* Bd = Ad + BM*64;
    #pragma unroll
    for (int i=0;i<2;i++){
      int s = i*THREADS + t;
      int r = s>>2, g = s&3;
      int src = (g ^ ((r>>1)&3))*8;
      gload16(Ag + (size_t)r*lda + k0 + src, Ad + (i*THREADS + w*64)*16);
      gload16(Bg + (size_t)r*ldb + k0 + src, Bd + (i*THREADS + w*64)*16);
    }
  };

  #pragma unroll
  for (int p=0;p<NBUF-1;p++) STAGE(p, p);

  int cur = 0;
  for (int kt=0; kt<ntiles; ++kt){
    int rem = ntiles-1-kt;
    if (rem>=1)      asm volatile("s_waitcnt vmcnt(4)" ::: "memory");
    else             asm volatile("s_waitcnt vmcnt(0)" ::: "memory");
    __builtin_amdgcn_s_barrier();
    const u16* As = lds + (size_t)cur*BUFE;
    const u16* Bs = As + BM*32;
    bf16x8 af[MR], bf[NR];
    #pragma unroll
    for (int i=0;i<MR;i++){
      int r = wr*(MR*16) + i*16 + lane16;
      int g = lg ^ ((r>>1)&3);
      af[i] = *(const bf16x8*)(As + r*32 + g*8);
    }
    #pragma unroll
    for (int j=0;j<NR;j++){
      int r = wc*(NR*16) + j*16 + lane16;
      int g = lg ^ ((r>>1)&3);
      bf[j] = *(const bf16x8*)(Bs + r*32 + g*8);
    }
    int st = kt + NBUF-1;
    if (st < ntiles) STAGE(st, (cur==0)?(NBUF-1):(cur-1));
    __builtin_amdgcn_s_setprio(1);
    #pragma unroll
    for (int i=0;i<MR;i++)
      #pragma unroll
      for (int j=0;j<NR;j++)
        acc[i][j] = __builtin_amdgcn_mfma_f32_16x16x32_bf16(af[i], bf[j], acc[i][j], 0,0,0);
    __builtin_amdgcn_s_setprio(0);
    __builtin_amdgcn_sched_barrier(0);
    cur = (cur+1==NBUF)?0:(cur+1);
  }

  if constexpr (EPI==0){
    int region = (n0 < 3072) ? (int)(n0>>10) : 3;
    if (region<=1){
      u16* dst = (region==0)? qh : kh;
      float sc = (region==0)? 0.125f*1.44269504f : 1.0f;   // fold 1/8 and log2(e)
      int h = (int)((n0 & 1023)>>6) + wc;
      int d = lane16;
      #pragma unroll
      for (int i=0;i<MR;i++){
        #pragma unroll
        for (int r=0;r<4;r++){
          int row = (int)m0 + wr*(MR*16) + i*16 + lg*4 + r;
          int bb = row>>11, s = row&2047;
          float cs = tab[s*32+d], sn = tab[s*32+16+d];
          float x0 = acc[i][0][r], x1 = acc[i][1][r];
          size_t base = ((size_t)(bb*16+h)*SLEN + s)*64;
          dst[base+d]    = f2b((x0*cs - x1*sn)*sc);
          dst[base+16+d] = f2b((x1*cs + x0*sn)*sc);
          dst[base+32+d] = f2b(acc[i][2][r]*sc);
          dst[base+48+d] = f2b(acc[i][3][r]*sc);
        }
      }
    } else if (region==2){
      // direct vT write: vT (B,H,64,S), 4 consecutive s per lane packed as uint2
      #pragma unroll
      for (int j=0;j<NR;j++){
        int cv = (int)(n0-2048) + wc*(NR*16) + j*16 + lane16;
        int hh = cv>>6, dd = cv&63;
        #pragma unroll
        for (int i=0;i<MR;i++){
          int row0 = (int)m0 + wr*(MR*16) + i*16 + lg*4;
          int bb = row0>>11, s0 = row0&2047;
          union { u16 o[4]; uint2 v; } pk2;
          #pragma unroll
          for (int r=0;r<4;r++) pk2.o[r] = f2b(acc[i][j][r]);
          *(uint2*)(vt + ((size_t)(bb*16+hh)*64 + dd)*SLEN + s0) = pk2.v;
        }
      }
    } else {
      int fbase = (int)((n0-3072)>>1) + wc*(NR*8) + lane16;
      #pragma unroll
      for (int i=0;i<MR;i++)
        #pragma unroll
        for (int p=0;p<NR/2;p++){
          int col = 1024 + fbase + p*16;
          #pragma unroll
          for (int r=0;r<4;r++){
            int row = (int)m0 + wr*(MR*16) + i*16 + lg*4 + r;
            float fv = acc[i][2*p][r];
            float gv = acc[i][2*p+1][r];
            float tz = 0.7978845608f*(gv + 0.044715f*gv*gv*gv);
            float th = 1.f - 2.f/(__expf(2.f*tz)+1.f);
            afinal[(size_t)row*NFUSE + col] = f2b(fv * 0.5f*gv*(1.f+th));
          }
        }
    }
  } else {
    u16* pbs = pb + (size_t)blockIdx.z*MROWS*DMODEL;
    #pragma unroll
    for (int i=0;i<MR;i++)
      #pragma unroll
      for (int j=0;j<NR;j++){
        int col = (int)n0 + wc*(NR*16) + j*16 + lane16;
        #pragma unroll
        for (int r=0;r<4;r++){
          int row = (int)m0 + wr*(MR*16) + i*16 + lg*4 + r;
          pbs[(size_t)row*DMODEL + col] = f2b(acc[i][j][r]);
        }
      }
  }
}

// ---------------- reduce 2 bf16 partials + residual + bias ----------------
__global__ __launch_bounds__(256) void k_reduce(const u16* __restrict__ pb, const float* __restrict__ resid,
                                                const float* __restrict__ bias, float* __restrict__ out){
  size_t i8 = ((size_t)blockIdx.x*256 + threadIdx.x)*8;
  uint4 a0 = *(const uint4*)(pb + i8);
  uint4 a1 = *(const uint4*)(pb + (size_t)MROWS*DMODEL + i8);
  const u16* p0 = (const u16*)&a0;
  const u16* p1 = (const u16*)&a1;
  float4 r0 = *(const float4*)(resid + i8);
  float4 r1 = *(const float4*)(resid + i8 + 4);
  int bcol = (int)(i8 & 1023);
  float4 b0 = *(const float4*)(bias + bcol);
  float4 b1 = *(const float4*)(bias + bcol + 4);
  float4 o0, o1;
  const float* rr0 = (const float*)&r0; const float* bb0 = (const float*)&b0;
  const float* rr1 = (const float*)&r1; const float* bb1 = (const float*)&b1;
  float* oo0 = (float*)&o0; float* oo1 = (float*)&o1;
  #pragma unroll
  for (int k=0;k<4;k++){
    oo0[k] = b2f(p0[k]) + b2f(p1[k]) + rr0[k] + bb0[k];
    oo1[k] = b2f(p0[4+k]) + b2f(p1[4+k]) + rr1[k] + bb1[k];
  }
  *(float4*)(out + i8)     = o0;
  *(float4*)(out + i8 + 4) = o1;
}

// ---------------- flash attention: QBLK=128, full KV, fixed-shift softmax, sum-via-MFMA ----------------
#define M0SHIFT 20.0f
__global__ __launch_bounds__(256,3) void k_attn(const u16* __restrict__ qh, const u16* __restrict__ kh,
                                                const u16* __restrict__ vt, u16* __restrict__ afinal){
  __shared__ __attribute__((aligned(16))) u16 Klds[2][64*64];
  __shared__ __attribute__((aligned(16))) u16 Vlds[2][64*64];
  __shared__ __attribute__((aligned(16))) u16 Plds[4][32*72];
  // head->XCD swizzle: 512 blocks; XCD c hosts 4 heads, KV (2MB) stays L2-resident
  int p = (blockIdx.z*16 + blockIdx.y)*16 + blockIdx.x;   // 0..511
  int c = p&7, k = p>>3;                                  // k: 0..63
  int hb = c + 8*(k&3);                                   // 0..31 = b*16+h
  int qx = k>>2;                                          // 0..15
  int b = hb>>4, h = hb&15, q0 = qx*128;
  int t = threadIdx.x, w = t>>6, l = t&63;
  int lane16 = l&15, lg = l>>4;
  size_t hoff = (size_t)hb*SLEN*64;
  const u16* Qb = qh + hoff + (size_t)(q0 + w*32)*64;
  const u16* Kb = kh + hoff;
  const u16* Vb = vt + hoff;
  bf16x8 qf[2][2];
  #pragma unroll
  for (int mi=0;mi<2;mi++)
    #pragma unroll
    for (int ks=0;ks<2;ks++)
      qf[mi][ks] = *(const bf16x8*)(Qb + (size_t)(mi*16+lane16)*64 + ks*32 + lg*8);
  bf16x8 ones;
  #pragma unroll
  for (int i=0;i<8;i++) ones[i] = (__bf16)1.0f;
  f32x4 zero = {0.f,0.f,0.f,0.f};
  f32x4 acc[2][4];
  f32x4 lacc[2];
  #pragma unroll
  for (int mi=0;mi<2;mi++){
    lacc[mi] = zero;
    #pragma unroll
    for (int n=0;n<4;n++) acc[mi][n] = zero;
  }

  auto STAGE = [&](int buf, int kv0){
    #pragma unroll
    for (int r=0;r<2;r++){
      int cc = r*256 + t;
      int row = cc>>3;
      int g = (cc&7) ^ (row&7);
      gload16(Kb + (size_t)(kv0+row)*64 + g*8, (char*)Klds[buf] + r*4096 + w*1024);
      gload16(Vb + (size_t)row*SLEN + kv0 + g*8, (char*)Vlds[buf] + r*4096 + w*1024);
    }
  };

  STAGE(0, 0);
  __syncthreads();

  for (int tile=0; tile<32; ++tile){
    int cur = tile & 1;
    if (tile+1 < 32) STAGE(cur^1, (tile+1)*64);
    f32x4 sf[2][4];
    #pragma unroll
    for (int mi=0;mi<2;mi++)
      #pragma unroll
      for (int n=0;n<4;n++) sf[mi][n] = zero;
    __builtin_amdgcn_s_setprio(1);
    #pragma unroll
    for (int n=0;n<4;n++){
      #pragma unroll
      for (int ks=0;ks<2;ks++){
        int rk = n*16 + lane16;
        int g = (ks*4 + lg) ^ (rk&7);
        bf16x8 kf = *(const bf16x8*)(Klds[cur] + rk*64 + g*8);
        sf[0][n] = __builtin_amdgcn_mfma_f32_16x16x32_bf16(qf[0][ks], kf, sf[0][n], 0,0,0);
        sf[1][n] = __builtin_amdgcn_mfma_f32_16x16x32_bf16(qf[1][ks], kf, sf[1][n], 0,0,0);
      }
    }
    __builtin_amdgcn_s_setprio(0);
    #pragma unroll
    for (int mi=0;mi<2;mi++)
      #pragma unroll
      for (int jr=0;jr<4;jr++)
        #pragma unroll
        for (int n=0;n<4;n++){
          float pv = fexp2(sf[mi][n][jr] - M0SHIFT);
          u32 u; __builtin_memcpy(&u,&pv,4);
          Plds[w][(mi*16 + lg*4 + jr)*72 + n*16 + lane16] = (u16)(u>>16);
        }
    __builtin_amdgcn_s_setprio(1);
    #pragma unroll
    for (int ks=0;ks<2;ks++){
      bf16x8 vf[4];
      #pragma unroll
      for (int n=0;n<4;n++){
        int rv = n*16 + lane16;
        int g = (ks*4 + lg) ^ (rv&7);
        vf[n] = *(const bf16x8*)(Vlds[cur] + rv*64 + g*8);
      }
      #pragma unroll
      for (int mi=0;mi<2;mi++){
        bf16x8 pa = *(const bf16x8*)(&Plds[w][(mi*16 + lane16)*72 + ks*32 + lg*8]);
        #pragma unroll
        for (int n=0;n<4;n++)
          acc[mi][n] = __builtin_amdgcn_mfma_f32_16x16x32_bf16(pa, vf[n], acc[mi][n], 0,0,0);
        lacc[mi] = __builtin_amdgcn_mfma_f32_16x16x32_bf16(pa, ones, lacc[mi], 0,0,0);
      }
    }
    __builtin_amdgcn_s_setprio(0);
    __syncthreads();
  }
  // normalize and write bf16 directly to afinal cols 0..1023
  #pragma unroll
  for (int mi=0;mi<2;mi++){
    float inv[4];
    #pragma unroll
    for (int jr=0;jr<4;jr++) inv[jr] = 1.f/lacc[mi][jr];
    #pragma unroll
    for (int n=0;n<4;n++)
      #pragma unroll
      for (int jr=0;jr<4;jr++){
        int srow = q0 + w*32 + mi*16 + lg*4 + jr;
        int col = h*64 + n*16 + lane16;
        afinal[(size_t)(b*SLEN+srow)*NFUSE + col] = f2b(acc[mi][n][jr]*inv[jr]);
      }
  }
}

// ---------------- launch ----------------
extern "C" void kernel_launch(void* const* d_in, const int* in_sizes, int n_in,
                              void* d_out, int out_size, void* d_ws, size_t ws_size,
                              hipStream_t stream) {
  const float* inputs = (const float*)d_in[0];
  const float* te     = (const float*)d_in[1];
  const float* ln_w   = (const float*)d_in[2];
  const float* ln_b   = (const float*)d_in[3];
  const float* cond_w = (const float*)d_in[4];
  const float* cond_b = (const float*)d_in[5];
  const float* w_in   = (const float*)d_in[6];
  const float* w_attn = (const float*)d_in[7];
  const float* w_ff   = (const float*)d_in[8];
  const float* b_ff   = (const float*)d_in[9];
  float* out = (float*)d_out;

  char* ws = (char*)d_ws;
  size_t off = 0;
  auto alloc = [&](size_t n)->char*{ char* p = ws + off; off += (n + 255) & ~(size_t)255; return p; };
  u16*  w_inT    = (u16*)alloc((size_t)NPROJ*DMODEL*2);
  u16*  w_fusedT = (u16*)alloc((size_t)DMODEL*NFUSE*2);
  u16*  units    = (u16*)alloc((size_t)MROWS*DMODEL*2);
  u16*  qh       = (u16*)alloc((size_t)MROWS*DMODEL*2);
  u16*  kh       = (u16*)alloc((size_t)MROWS*DMODEL*2);
  u16*  vT       = (u16*)alloc((size_t)MROWS*DMODEL*2);
  u16*  afinal   = (u16*)alloc((size_t)MROWS*NFUSE*2);
  u16*  pb       = (u16*)alloc((size_t)2*MROWS*DMODEL*2);
  float* cond    = (float*)alloc(2*2048*4);
  float* ropetab = (float*)alloc((size_t)SLEN*32*4);
  (void)ws_size; (void)in_sizes; (void)n_in; (void)out_size;

  // weight prep + rope table + cond (one launch)
  k_prep<<<dim3(16384+128+16), 256, 0, stream>>>(w_in, w_attn, w_ff, te, cond_w, cond_b,
                                                 w_inT, w_fusedT, ropetab, cond);
  // LN + modulation
  k_ln<<<MROWS, 256, 0, stream>>>(inputs, ln_w, ln_b, cond, units);
  // fused qkv/ff projection: 128x128, NBUF=3 (48KB LDS -> 3 blocks/CU), fused epilogue (vT direct)
  k_gemm_pipe<128,128,2,2,3,3,0><<<dim3(NPROJ/128, MROWS/128), 256, 0, stream>>>(
      units, w_inT, DMODEL, DMODEL, DMODEL, ropetab, qh, kh, vT, afinal, nullptr);
  // attention -> afinal cols 0..1023 (QBLK=128, direct normalized write)
  k_attn<<<dim3(16, 16, 2), 256, 0, stream>>>(qh, kh, vT, afinal);
  // final fused GEMM: split-K x2 bf16 partials (pipelined 128x128, NBUF=3), then reduce
  k_gemm_pipe<128,128,2,2,3,3,1><<<dim3(DMODEL/128, MROWS/128, 2), 256, 0, stream>>>(
      afinal, w_fusedT, 2560, NFUSE, NFUSE, nullptr, nullptr, nullptr, nullptr, nullptr, pb);
  k_reduce<<<dim3(MROWS*DMODEL/2048), 256, 0, stream>>>(pb, inputs, b_ff, out);
}

// Round 13
// 288.360 us; speedup vs baseline: 1.0471x; 1.0471x over previous
//
#include <hip/hip_runtime.h>
#include <hip/hip_bf16.h>

typedef __attribute__((ext_vector_type(8))) __bf16 bf16x8;
typedef __attribute__((ext_vector_type(4))) float f32x4;
typedef unsigned short u16;
typedef unsigned int u32;

#define DMODEL 1024
#define SLEN   2048
#define NPROJ  11264
#define NFUSE  5120
#define MROWS  4096

__device__ __forceinline__ float b2f(u16 u){ u32 v=((u32)u)<<16; float f; __builtin_memcpy(&f,&v,4); return f; }
__device__ __forceinline__ u16 f2b(float f){ u32 u; __builtin_memcpy(&u,&f,4); u32 r=u+0x7fffu+((u>>16)&1u); return (u16)(r>>16); }
__device__ __forceinline__ float fexp2(float x){ return __builtin_amdgcn_exp2f(x); }

__device__ __forceinline__ void gload16(const void* g, void* l){
  __builtin_amdgcn_global_load_lds((__attribute__((address_space(1))) u32*)g,
                                   (__attribute__((address_space(3))) u32*)l, 16, 0, 0);
}

// ---------------- fused prep: 3 weight transposes + rope table + cond, one launch ----------------
__global__ __launch_bounds__(256) void k_prep(const float* __restrict__ w_in,
                                              const float* __restrict__ w_attn,
                                              const float* __restrict__ w_ff,
                                              const float* __restrict__ te,
                                              const float* __restrict__ cond_w,
                                              const float* __restrict__ cond_b,
                                              u16* __restrict__ w_inT,
                                              u16* __restrict__ w_fusedT,
                                              float* __restrict__ ropetab,
                                              float* __restrict__ cond){
  __shared__ float tile[32][33];
  __shared__ float sl[DMODEL];
  int bid = blockIdx.x;
  if (bid >= 16384){
    int xb = bid - 16384;
    if (xb < 128){
      int idx = xb*256 + threadIdx.x;
      int s = idx >> 4, i = idx & 15;
      float inv = powf(10000.f, -(float)i/16.f);
      float f = (float)s * inv;
      ropetab[s*32 + i]      = cosf(f);
      ropetab[s*32 + 16 + i] = sinf(f);
    } else {
      int cb2 = xb - 128;
      int b = cb2>>3, t = threadIdx.x;
      for (int i=t;i<DMODEL;i+=256){ float x = te[b*DMODEL+i]; sl[i] = x/(1.f+expf(-x)); }
      __syncthreads();
      int n = (cb2&7)*256 + t;
      float acc = 0.f;
      for (int k=0;k<DMODEL;k++) acc += sl[k]*cond_w[(size_t)k*2048 + n];
      cond[b*2048+n] = acc + cond_b[n];
    }
    return;
  }
  const float* src; u16* dst; int N, ldd, coloff, nx, remap, tix;
  if (bid < 11264){ tix=bid;       nx=352; src=w_in;   N=NPROJ;  dst=w_inT;    ldd=DMODEL; coloff=0;    remap=1; }
  else if (bid < 12288){ tix=bid-11264; nx=32; src=w_attn; N=DMODEL; dst=w_fusedT; ldd=NFUSE; coloff=0;    remap=0; }
  else {            tix=bid-12288; nx=32;  src=w_ff;   N=DMODEL; dst=w_fusedT; ldd=NFUSE;  coloff=1024; remap=0; }
  int n0 = (tix%nx)*32, k0 = (tix/nx)*32;
  int tx = threadIdx.x & 31, ty = threadIdx.x >> 5;
  int srccol;
  if (remap && (n0 + tx) >= 3072){
    int c = n0 + tx - 3072;
    int q = c >> 5, o = c & 31;
    srccol = (o < 16) ? (3072 + 16*q + o) : (7168 + 16*q + (o-16));
  } else srccol = n0 + tx;
  #pragma unroll
  for (int r=0;r<4;r++)
    tile[ty*4+r][tx] = src[(size_t)(k0+ty*4+r)*N + srccol];
  __syncthreads();
  #pragma unroll
  for (int r=0;r<4;r++){
    int n = ty*4+r;
    dst[(size_t)(n0+n)*ldd + coloff + k0 + tx] = f2b(tile[tx][n]);
  }
}

// ---------------- LayerNorm + modulation -> units bf16 ----------------
__global__ __launch_bounds__(256) void k_ln(const float* __restrict__ x, const float* __restrict__ lw,
                                            const float* __restrict__ lb, const float* __restrict__ cond,
                                            u16* __restrict__ units){
  int row = blockIdx.x; int b = row >> 11;
  int t = threadIdx.x;
  const float4 v = *(const float4*)(x + (size_t)row*DMODEL + t*4);
  float s = v.x+v.y+v.z+v.w;
  float q = v.x*v.x+v.y*v.y+v.z*v.z+v.w*v.w;
  #pragma unroll
  for (int off=32; off; off>>=1){ s += __shfl_xor(s,off); q += __shfl_xor(q,off); }
  __shared__ float red[8];
  int w = t>>6, l = t&63;
  if (l==0){ red[w]=s; red[4+w]=q; }
  __syncthreads();
  float S = red[0]+red[1]+red[2]+red[3];
  float Q = red[4]+red[5]+red[6]+red[7];
  float mu = S*(1.f/1024.f);
  float var = Q*(1.f/1024.f) - mu*mu;
  float rstd = rsqrtf(var + 1e-5f);
  int c0 = t*4;
  u16 o[4];
  const float* vf = (const float*)&v;
  #pragma unroll
  for (int i=0;i<4;i++){
    int c = c0+i;
    float nrm = (vf[i]-mu)*rstd*lw[c] + lb[c];
    float outv = (1.f + cond[b*2048 + c])*nrm + cond[b*2048 + 1024 + c];
    o[i] = f2b(outv);
  }
  u32 p0 = (u32)o[0] | ((u32)o[1]<<16);
  u32 p1 = (u32)o[2] | ((u32)o[3]<<16);
  uint2 pk; pk.x = p0; pk.y = p1;
  *(uint2*)(units + (size_t)row*DMODEL + c0) = pk;
}

// ================= pipelined GEMM: counted-vmcnt, raw barriers, NBUF LDS buffers =================
// COLUMN-major XCD decode (co-resident blocks share a B panel -> L2-resident).
// EPI 0: proj epilogue (rope/headsplit/vT-direct/ff-gate). EPI 1: split-K bf16 partials.
template<int BM,int BN,int WM,int WN,int NBUF,int MINW,int EPI>
__global__ __launch_bounds__(WM*WN*64, MINW) void k_gemm_pipe(
    const u16* __restrict__ A, const u16* __restrict__ Bt, int K, int lda, int ldb,
    const float* __restrict__ tab, u16* __restrict__ qh, u16* __restrict__ kh,
    u16* __restrict__ vt, u16* __restrict__ afinal, u16* __restrict__ pb)
{
  constexpr int THREADS = WM*WN*64;
  constexpr int MR = BM/WM/16, NR = BN/WN/16;
  constexpr int BUFE = (BM+BN)*32;
  __shared__ __attribute__((aligned(16))) u16 lds[NBUF*BUFE];
  int t = threadIdx.x, w = t>>6, l = t&63;
  int wr = w/WN, wc = w%WN;
  int lane16 = l&15, lg = l>>4;

  int nbx = gridDim.x, nby = gridDim.y;
  int wg = blockIdx.y*nbx + blockIdx.x;
  int nwg = nbx*nby;
  int cpx = nwg>>3;
  int swz = (wg&7)*cpx + (wg>>3);
  int bx = swz / nby, by = swz - bx*nby;   // column-major: co-resident share B panel

  size_t m0 = (size_t)by*BM, n0 = (size_t)bx*BN;
  int koff = (EPI==1) ? blockIdx.z*2560 : 0;
  const u16* Ag = A + m0*lda + koff;
  const u16* Bg = Bt + n0*ldb + koff;

  f32x4 zero = {0.f,0.f,0.f,0.f};
  f32x4 acc[MR][NR];
  #pragma unroll
  for (int i=0;i<MR;i++)
    #pragma unroll
    for (int j=0;j<NR;j++) acc[i][j] = zero;

  const int ntiles = K/32;

  auto STAGE = [&](int tt, int buf){
    int k0 = tt*32;
    char* Ad = (char*)lds + (size_t)buf*(BUFE*2);
    char* Bd = Ad + BM*64;
    #pragma unroll
    for (int i=0;i<2;i++){
      int s = i*THREADS + t;
      int r = s>>2, g = s&3;
      int src = (g ^ ((r>>1)&3))*8;
      gload16(Ag + (size_t)r*lda + k0 + src, Ad + (i*THREADS + w*64)*16);
      gload16(Bg + (size_t)r*ldb + k0 + src, Bd + (i*THREADS + w*64)*16);
    }
  };

  #pragma unroll
  for (int p=0;p<NBUF-1;p++) STAGE(p, p);

  int cur = 0;
  for (int kt=0; kt<ntiles; ++kt){
    int rem = ntiles-1-kt;
    if (rem>=1)      asm volatile("s_waitcnt vmcnt(4)" ::: "memory");
    else             asm volatile("s_waitcnt vmcnt(0)" ::: "memory");
    __builtin_amdgcn_s_barrier();
    const u16* As = lds + (size_t)cur*BUFE;
    const u16* Bs = As + BM*32;
    bf16x8 af[MR], bf[NR];
    #pragma unroll
    for (int i=0;i<MR;i++){
      int r = wr*(MR*16) + i*16 + lane16;
      int g = lg ^ ((r>>1)&3);
      af[i] = *(const bf16x8*)(As + r*32 + g*8);
    }
    #pragma unroll
    for (int j=0;j<NR;j++){
      int r = wc*(NR*16) + j*16 + lane16;
      int g = lg ^ ((r>>1)&3);
      bf[j] = *(const bf16x8*)(Bs + r*32 + g*8);
    }
    int st = kt + NBUF-1;
    if (st < ntiles) STAGE(st, (cur==0)?(NBUF-1):(cur-1));
    __builtin_amdgcn_s_setprio(1);
    #pragma unroll
    for (int i=0;i<MR;i++)
      #pragma unroll
      for (int j=0;j<NR;j++)
        acc[i][j] = __builtin_amdgcn_mfma_f32_16x16x32_bf16(af[i], bf[j], acc[i][j], 0,0,0);
    __builtin_amdgcn_s_setprio(0);
    __builtin_amdgcn_sched_barrier(0);
    cur = (cur+1==NBUF)?0:(cur+1);
  }

  if constexpr (EPI==0){
    int region = (n0 < 3072) ? (int)(n0>>10) : 3;
    if (region<=1){
      u16* dst = (region==0)? qh : kh;
      float sc = (region==0)? 0.125f*1.44269504f : 1.0f;   // fold 1/8 and log2(e)
      int h = (int)((n0 & 1023)>>6) + wc;
      int d = lane16;
      #pragma unroll
      for (int i=0;i<MR;i++){
        #pragma unroll
        for (int r=0;r<4;r++){
          int row = (int)m0 + wr*(MR*16) + i*16 + lg*4 + r;
          int bb = row>>11, s = row&2047;
          float cs = tab[s*32+d], sn = tab[s*32+16+d];
          float x0 = acc[i][0][r], x1 = acc[i][1][r];
          size_t base = ((size_t)(bb*16+h)*SLEN + s)*64;
          dst[base+d]    = f2b((x0*cs - x1*sn)*sc);
          dst[base+16+d] = f2b((x1*cs + x0*sn)*sc);
          dst[base+32+d] = f2b(acc[i][2][r]*sc);
          dst[base+48+d] = f2b(acc[i][3][r]*sc);
        }
      }
    } else if (region==2){
      // direct vT write: vT (B,H,64,S), 4 consecutive s per lane packed as uint2
      #pragma unroll
      for (int j=0;j<NR;j++){
        int cv = (int)(n0-2048) + wc*(NR*16) + j*16 + lane16;
        int hh = cv>>6, dd = cv&63;
        #pragma unroll
        for (int i=0;i<MR;i++){
          int row0 = (int)m0 + wr*(MR*16) + i*16 + lg*4;
          int bb = row0>>11, s0 = row0&2047;
          union { u16 o[4]; uint2 v; } pk2;
          #pragma unroll
          for (int r=0;r<4;r++) pk2.o[r] = f2b(acc[i][j][r]);
          *(uint2*)(vt + ((size_t)(bb*16+hh)*64 + dd)*SLEN + s0) = pk2.v;
        }
      }
    } else {
      int fbase = (int)((n0-3072)>>1) + wc*(NR*8) + lane16;
      #pragma unroll
      for (int i=0;i<MR;i++)
        #pragma unroll
        for (int p=0;p<NR/2;p++){
          int col = 1024 + fbase + p*16;
          #pragma unroll
          for (int r=0;r<4;r++){
            int row = (int)m0 + wr*(MR*16) + i*16 + lg*4 + r;
            float fv = acc[i][2*p][r];
            float gv = acc[i][2*p+1][r];
            float tz = 0.7978845608f*(gv + 0.044715f*gv*gv*gv);
            float th = 1.f - 2.f/(__expf(2.f*tz)+1.f);
            afinal[(size_t)row*NFUSE + col] = f2b(fv * 0.5f*gv*(1.f+th));
          }
        }
    }
  } else {
    u16* pbs = pb + (size_t)blockIdx.z*MROWS*DMODEL;
    #pragma unroll
    for (int i=0;i<MR;i++)
      #pragma unroll
      for (int j=0;j<NR;j++){
        int col = (int)n0 + wc*(NR*16) + j*16 + lane16;
        #pragma unroll
        for (int r=0;r<4;r++){
          int row = (int)m0 + wr*(MR*16) + i*16 + lg*4 + r;
          pbs[(size_t)row*DMODEL + col] = f2b(acc[i][j][r]);
        }
      }
  }
}

// ---------------- reduce 2 bf16 partials + residual + bias ----------------
__global__ __launch_bounds__(256) void k_reduce(const u16* __restrict__ pb, const float* __restrict__ resid,
                                                const float* __restrict__ bias, float* __restrict__ out){
  size_t i8 = ((size_t)blockIdx.x*256 + threadIdx.x)*8;
  uint4 a0 = *(const uint4*)(pb + i8);
  uint4 a1 = *(const uint4*)(pb + (size_t)MROWS*DMODEL + i8);
  const u16* p0 = (const u16*)&a0;
  const u16* p1 = (const u16*)&a1;
  float4 r0 = *(const float4*)(resid + i8);
  float4 r1 = *(const float4*)(resid + i8 + 4);
  int bcol = (int)(i8 & 1023);
  float4 b0 = *(const float4*)(bias + bcol);
  float4 b1 = *(const float4*)(bias + bcol + 4);
  float4 o0, o1;
  const float* rr0 = (const float*)&r0; const float* bb0 = (const float*)&b0;
  const float* rr1 = (const float*)&r1; const float* bb1 = (const float*)&b1;
  float* oo0 = (float*)&o0; float* oo1 = (float*)&o1;
  #pragma unroll
  for (int k=0;k<4;k++){
    oo0[k] = b2f(p0[k]) + b2f(p1[k]) + rr0[k] + bb0[k];
    oo1[k] = b2f(p0[4+k]) + b2f(p1[4+k]) + rr1[k] + bb1[k];
  }
  *(float4*)(out + i8)     = o0;
  *(float4*)(out + i8 + 4) = o1;
}

// ---------------- flash attention: QBLK=128, full KV, fixed-shift softmax, sum-via-MFMA ----------------
#define M0SHIFT 20.0f
__global__ __launch_bounds__(256,3) void k_attn(const u16* __restrict__ qh, const u16* __restrict__ kh,
                                                const u16* __restrict__ vt, u16* __restrict__ afinal){
  __shared__ __attribute__((aligned(16))) u16 Klds[2][64*64];
  __shared__ __attribute__((aligned(16))) u16 Vlds[2][64*64];
  __shared__ __attribute__((aligned(16))) u16 Plds[4][32*72];
  // head->XCD swizzle: 512 blocks; XCD c hosts 4 heads, KV (2MB) stays L2-resident
  int p = (blockIdx.z*16 + blockIdx.y)*16 + blockIdx.x;   // 0..511
  int c = p&7, k = p>>3;                                  // k: 0..63
  int hb = c + 8*(k&3);                                   // 0..31 = b*16+h
  int qx = k>>2;                                          // 0..15
  int b = hb>>4, h = hb&15, q0 = qx*128;
  int t = threadIdx.x, w = t>>6, l = t&63;
  int lane16 = l&15, lg = l>>4;
  size_t hoff = (size_t)hb*SLEN*64;
  const u16* Qb = qh + hoff + (size_t)(q0 + w*32)*64;
  const u16* Kb = kh + hoff;
  const u16* Vb = vt + hoff;
  bf16x8 qf[2][2];
  #pragma unroll
  for (int mi=0;mi<2;mi++)
    #pragma unroll
    for (int ks=0;ks<2;ks++)
      qf[mi][ks] = *(const bf16x8*)(Qb + (size_t)(mi*16+lane16)*64 + ks*32 + lg*8);
  bf16x8 ones;
  #pragma unroll
  for (int i=0;i<8;i++) ones[i] = (__bf16)1.0f;
  f32x4 zero = {0.f,0.f,0.f,0.f};
  f32x4 acc[2][4];
  f32x4 lacc[2];
  #pragma unroll
  for (int mi=0;mi<2;mi++){
    lacc[mi] = zero;
    #pragma unroll
    for (int n=0;n<4;n++) acc[mi][n] = zero;
  }

  auto STAGE = [&](int buf, int kv0){
    #pragma unroll
    for (int r=0;r<2;r++){
      int cc = r*256 + t;
      int row = cc>>3;
      int g = (cc&7) ^ (row&7);
      gload16(Kb + (size_t)(kv0+row)*64 + g*8, (char*)Klds[buf] + r*4096 + w*1024);
      gload16(Vb + (size_t)row*SLEN + kv0 + g*8, (char*)Vlds[buf] + r*4096 + w*1024);
    }
  };

  STAGE(0, 0);
  __syncthreads();

  for (int tile=0; tile<32; ++tile){
    int cur = tile & 1;
    if (tile+1 < 32) STAGE(cur^1, (tile+1)*64);
    f32x4 sf[2][4];
    #pragma unroll
    for (int mi=0;mi<2;mi++)
      #pragma unroll
      for (int n=0;n<4;n++) sf[mi][n] = zero;
    __builtin_amdgcn_s_setprio(1);
    #pragma unroll
    for (int n=0;n<4;n++){
      #pragma unroll
      for (int ks=0;ks<2;ks++){
        int rk = n*16 + lane16;
        int g = (ks*4 + lg) ^ (rk&7);
        bf16x8 kf = *(const bf16x8*)(Klds[cur] + rk*64 + g*8);
        sf[0][n] = __builtin_amdgcn_mfma_f32_16x16x32_bf16(qf[0][ks], kf, sf[0][n], 0,0,0);
        sf[1][n] = __builtin_amdgcn_mfma_f32_16x16x32_bf16(qf[1][ks], kf, sf[1][n], 0,0,0);
      }
    }
    __builtin_amdgcn_s_setprio(0);
    #pragma unroll
    for (int mi=0;mi<2;mi++)
      #pragma unroll
      for (int jr=0;jr<4;jr++)
        #pragma unroll
        for (int n=0;n<4;n++){
          float pv = fexp2(sf[mi][n][jr] - M0SHIFT);
          u32 u; __builtin_memcpy(&u,&pv,4);
          Plds[w][(mi*16 + lg*4 + jr)*72 + n*16 + lane16] = (u16)(u>>16);
        }
    __builtin_amdgcn_s_setprio(1);
    #pragma unroll
    for (int ks=0;ks<2;ks++){
      bf16x8 vf[4];
      #pragma unroll
      for (int n=0;n<4;n++){
        int rv = n*16 + lane16;
        int g = (ks*4 + lg) ^ (rv&7);
        vf[n] = *(const bf16x8*)(Vlds[cur] + rv*64 + g*8);
      }
      #pragma unroll
      for (int mi=0;mi<2;mi++){
        bf16x8 pa = *(const bf16x8*)(&Plds[w][(mi*16 + lane16)*72 + ks*32 + lg*8]);
        #pragma unroll
        for (int n=0;n<4;n++)
          acc[mi][n] = __builtin_amdgcn_mfma_f32_16x16x32_bf16(pa, vf[n], acc[mi][n], 0,0,0);
        lacc[mi] = __builtin_amdgcn_mfma_f32_16x16x32_bf16(pa, ones, lacc[mi], 0,0,0);
      }
    }
    __builtin_amdgcn_s_setprio(0);
    __syncthreads();
  }
  // normalize and write bf16 directly to afinal cols 0..1023
  #pragma unroll
  for (int mi=0;mi<2;mi++){
    float inv[4];
    #pragma unroll
    for (int jr=0;jr<4;jr++) inv[jr] = 1.f/lacc[mi][jr];
    #pragma unroll
    for (int n=0;n<4;n++)
      #pragma unroll
      for (int jr=0;jr<4;jr++){
        int srow = q0 + w*32 + mi*16 + lg*4 + jr;
        int col = h*64 + n*16 + lane16;
        afinal[(size_t)(b*SLEN+srow)*NFUSE + col] = f2b(acc[mi][n][jr]*inv[jr]);
      }
  }
}

// ---------------- launch ----------------
extern "C" void kernel_launch(void* const* d_in, const int* in_sizes, int n_in,
                              void* d_out, int out_size, void* d_ws, size_t ws_size,
                              hipStream_t stream) {
  const float* inputs = (const float*)d_in[0];
  const float* te     = (const float*)d_in[1];
  const float* ln_w   = (const float*)d_in[2];
  const float* ln_b   = (const float*)d_in[3];
  const float* cond_w = (const float*)d_in[4];
  const float* cond_b = (const float*)d_in[5];
  const float* w_in   = (const float*)d_in[6];
  const float* w_attn = (const float*)d_in[7];
  const float* w_ff   = (const float*)d_in[8];
  const float* b_ff   = (const float*)d_in[9];
  float* out = (float*)d_out;

  char* ws = (char*)d_ws;
  size_t off = 0;
  auto alloc = [&](size_t n)->char*{ char* p = ws + off; off += (n + 255) & ~(size_t)255; return p; };
  u16*  w_inT    = (u16*)alloc((size_t)NPROJ*DMODEL*2);
  u16*  w_fusedT = (u16*)alloc((size_t)DMODEL*NFUSE*2);
  u16*  units    = (u16*)alloc((size_t)MROWS*DMODEL*2);
  u16*  qh       = (u16*)alloc((size_t)MROWS*DMODEL*2);
  u16*  kh       = (u16*)alloc((size_t)MROWS*DMODEL*2);
  u16*  vT       = (u16*)alloc((size_t)MROWS*DMODEL*2);
  u16*  afinal   = (u16*)alloc((size_t)MROWS*NFUSE*2);
  u16*  pb       = (u16*)alloc((size_t)2*MROWS*DMODEL*2);
  float* cond    = (float*)alloc(2*2048*4);
  float* ropetab = (float*)alloc((size_t)SLEN*32*4);
  (void)ws_size; (void)in_sizes; (void)n_in; (void)out_size;

  // weight prep + rope table + cond (one launch)
  k_prep<<<dim3(16384+128+16), 256, 0, stream>>>(w_in, w_attn, w_ff, te, cond_w, cond_b,
                                                 w_inT, w_fusedT, ropetab, cond);
  // LN + modulation
  k_ln<<<MROWS, 256, 0, stream>>>(inputs, ln_w, ln_b, cond, units);
  // fused qkv/ff projection: 256x256, NBUF=3 (96KB LDS), column XCD decode, fused epilogue (vT direct)
  k_gemm_pipe<256,256,2,4,3,2,0><<<dim3(NPROJ/256, MROWS/256), 512, 0, stream>>>(
      units, w_inT, DMODEL, DMODEL, DMODEL, ropetab, qh, kh, vT, afinal, nullptr);
  // attention -> afinal cols 0..1023 (QBLK=128, direct normalized write)
  k_attn<<<dim3(16, 16, 2), 256, 0, stream>>>(qh, kh, vT, afinal);
  // final fused GEMM: split-K x2 bf16 partials (pipelined 128x128, NBUF=3), then reduce
  k_gemm_pipe<128,128,2,2,3,3,1><<<dim3(DMODEL/128, MROWS/128, 2), 256, 0, stream>>>(
      afinal, w_fusedT, 2560, NFUSE, NFUSE, nullptr, nullptr, nullptr, nullptr, nullptr, pb);
  k_reduce<<<dim3(MROWS*DMODEL/2048), 256, 0, stream>>>(pb, inputs, b_ff, out);
}

// Round 14
// 282.159 us; speedup vs baseline: 1.0701x; 1.0220x over previous
//
#include <hip/hip_runtime.h>
#include <hip/hip_bf16.h>

typedef __attribute__((ext_vector_type(8))) __bf16 bf16x8;
typedef __attribute__((ext_vector_type(4))) float f32x4;
typedef unsigned short u16;
typedef unsigned int u32;

#define DMODEL 1024
#define SLEN   2048
#define NPROJ  11264
#define NFUSE  5120
#define MROWS  4096

__device__ __forceinline__ float b2f(u16 u){ u32 v=((u32)u)<<16; float f; __builtin_memcpy(&f,&v,4); return f; }
__device__ __forceinline__ u16 f2b(float f){ u32 u; __builtin_memcpy(&u,&f,4); u32 r=u+0x7fffu+((u>>16)&1u); return (u16)(r>>16); }
__device__ __forceinline__ float fexp2(float x){ return __builtin_amdgcn_exp2f(x); }

__device__ __forceinline__ void gload16(const void* g, void* l){
  __builtin_amdgcn_global_load_lds((__attribute__((address_space(1))) u32*)g,
                                   (__attribute__((address_space(3))) u32*)l, 16, 0, 0);
}

// ---------------- fused prep: 3 weight transposes + rope table + cond, one launch ----------------
__global__ __launch_bounds__(256) void k_prep(const float* __restrict__ w_in,
                                              const float* __restrict__ w_attn,
                                              const float* __restrict__ w_ff,
                                              const float* __restrict__ te,
                                              const float* __restrict__ cond_w,
                                              const float* __restrict__ cond_b,
                                              u16* __restrict__ w_inT,
                                              u16* __restrict__ w_fusedT,
                                              float* __restrict__ ropetab,
                                              float* __restrict__ cond){
  __shared__ float tile[32][33];
  __shared__ float sl[DMODEL];
  int bid = blockIdx.x;
  if (bid >= 16384){
    int xb = bid - 16384;
    if (xb < 128){
      int idx = xb*256 + threadIdx.x;
      int s = idx >> 4, i = idx & 15;
      float inv = powf(10000.f, -(float)i/16.f);
      float f = (float)s * inv;
      ropetab[s*32 + i]      = cosf(f);
      ropetab[s*32 + 16 + i] = sinf(f);
    } else {
      int cb2 = xb - 128;
      int b = cb2>>3, t = threadIdx.x;
      for (int i=t;i<DMODEL;i+=256){ float x = te[b*DMODEL+i]; sl[i] = x/(1.f+expf(-x)); }
      __syncthreads();
      int n = (cb2&7)*256 + t;
      float acc = 0.f;
      for (int k=0;k<DMODEL;k++) acc += sl[k]*cond_w[(size_t)k*2048 + n];
      cond[b*2048+n] = acc + cond_b[n];
    }
    return;
  }
  const float* src; u16* dst; int N, ldd, coloff, nx, remap, tix;
  if (bid < 11264){ tix=bid;       nx=352; src=w_in;   N=NPROJ;  dst=w_inT;    ldd=DMODEL; coloff=0;    remap=1; }
  else if (bid < 12288){ tix=bid-11264; nx=32; src=w_attn; N=DMODEL; dst=w_fusedT; ldd=NFUSE; coloff=0;    remap=0; }
  else {            tix=bid-12288; nx=32;  src=w_ff;   N=DMODEL; dst=w_fusedT; ldd=NFUSE;  coloff=1024; remap=0; }
  int n0 = (tix%nx)*32, k0 = (tix/nx)*32;
  int tx = threadIdx.x & 31, ty = threadIdx.x >> 5;
  int srccol;
  if (remap && (n0 + tx) >= 3072){
    int c = n0 + tx - 3072;
    int q = c >> 5, o = c & 31;
    srccol = (o < 16) ? (3072 + 16*q + o) : (7168 + 16*q + (o-16));
  } else srccol = n0 + tx;
  #pragma unroll
  for (int r=0;r<4;r++)
    tile[ty*4+r][tx] = src[(size_t)(k0+ty*4+r)*N + srccol];
  __syncthreads();
  #pragma unroll
  for (int r=0;r<4;r++){
    int n = ty*4+r;
    dst[(size_t)(n0+n)*ldd + coloff + k0 + tx] = f2b(tile[tx][n]);
  }
}

// ---------------- LayerNorm + modulation -> units bf16 ----------------
__global__ __launch_bounds__(256) void k_ln(const float* __restrict__ x, const float* __restrict__ lw,
                                            const float* __restrict__ lb, const float* __restrict__ cond,
                                            u16* __restrict__ units){
  int row = blockIdx.x; int b = row >> 11;
  int t = threadIdx.x;
  const float4 v = *(const float4*)(x + (size_t)row*DMODEL + t*4);
  float s = v.x+v.y+v.z+v.w;
  float q = v.x*v.x+v.y*v.y+v.z*v.z+v.w*v.w;
  #pragma unroll
  for (int off=32; off; off>>=1){ s += __shfl_xor(s,off); q += __shfl_xor(q,off); }
  __shared__ float red[8];
  int w = t>>6, l = t&63;
  if (l==0){ red[w]=s; red[4+w]=q; }
  __syncthreads();
  float S = red[0]+red[1]+red[2]+red[3];
  float Q = red[4]+red[5]+red[6]+red[7];
  float mu = S*(1.f/1024.f);
  float var = Q*(1.f/1024.f) - mu*mu;
  float rstd = rsqrtf(var + 1e-5f);
  int c0 = t*4;
  u16 o[4];
  const float* vf = (const float*)&v;
  #pragma unroll
  for (int i=0;i<4;i++){
    int c = c0+i;
    float nrm = (vf[i]-mu)*rstd*lw[c] + lb[c];
    float outv = (1.f + cond[b*2048 + c])*nrm + cond[b*2048 + 1024 + c];
    o[i] = f2b(outv);
  }
  u32 p0 = (u32)o[0] | ((u32)o[1]<<16);
  u32 p1 = (u32)o[2] | ((u32)o[3]<<16);
  uint2 pk; pk.x = p0; pk.y = p1;
  *(uint2*)(units + (size_t)row*DMODEL + c0) = pk;
}

// ================= pipelined GEMM: counted-vmcnt, raw barriers, NBUF LDS buffers =================
// CMAJ=1: column-major XCD decode (co-resident blocks share a B panel) — use when B is the LARGE operand.
// CMAJ=0: row-major (co-resident share an A panel) — use when B is small/L2-fittable.
// EPI 0: proj epilogue (rope/headsplit/vT-direct/ff-gate). EPI 1: split-K bf16 partials.
template<int BM,int BN,int WM,int WN,int NBUF,int MINW,int EPI,int CMAJ>
__global__ __launch_bounds__(WM*WN*64, MINW) void k_gemm_pipe(
    const u16* __restrict__ A, const u16* __restrict__ Bt, int K, int lda, int ldb,
    const float* __restrict__ tab, u16* __restrict__ qh, u16* __restrict__ kh,
    u16* __restrict__ vt, u16* __restrict__ afinal, u16* __restrict__ pb)
{
  constexpr int THREADS = WM*WN*64;
  constexpr int MR = BM/WM/16, NR = BN/WN/16;
  constexpr int BUFE = (BM+BN)*32;
  __shared__ __attribute__((aligned(16))) u16 lds[NBUF*BUFE];
  int t = threadIdx.x, w = t>>6, l = t&63;
  int wr = w/WN, wc = w%WN;
  int lane16 = l&15, lg = l>>4;

  int nbx = gridDim.x, nby = gridDim.y;
  int wg = blockIdx.y*nbx + blockIdx.x;
  int nwg = nbx*nby;
  int cpx = nwg>>3;
  int swz = (wg&7)*cpx + (wg>>3);
  int bx, by;
  if constexpr (CMAJ){ bx = swz / nby; by = swz - bx*nby; }
  else               { bx = swz % nbx; by = swz / nbx; }

  size_t m0 = (size_t)by*BM, n0 = (size_t)bx*BN;
  int koff = (EPI==1) ? blockIdx.z*2560 : 0;
  const u16* Ag = A + m0*lda + koff;
  const u16* Bg = Bt + n0*ldb + koff;

  f32x4 zero = {0.f,0.f,0.f,0.f};
  f32x4 acc[MR][NR];
  #pragma unroll
  for (int i=0;i<MR;i++)
    #pragma unroll
    for (int j=0;j<NR;j++) acc[i][j] = zero;

  const int ntiles = K/32;

  auto STAGE = [&](int tt, int buf){
    int k0 = tt*32;
    char* Ad = (char*)lds + (size_t)buf*(BUFE*2);
    char* Bd = Ad + BM*64;
    #pragma unroll
    for (int i=0;i<2;i++){
      int s = i*THREADS + t;
      int r = s>>2, g = s&3;
      int src = (g ^ ((r>>1)&3))*8;
      gload16(Ag + (size_t)r*lda + k0 + src, Ad + (i*THREADS + w*64)*16);
      gload16(Bg + (size_t)r*ldb + k0 + src, Bd + (i*THREADS + w*64)*16);
    }
  };

  #pragma unroll
  for (int p=0;p<NBUF-1;p++) STAGE(p, p);

  int cur = 0;
  for (int kt=0; kt<ntiles; ++kt){
    int rem = ntiles-1-kt;
    if (rem>=1)      asm volatile("s_waitcnt vmcnt(4)" ::: "memory");
    else             asm volatile("s_waitcnt vmcnt(0)" ::: "memory");
    __builtin_amdgcn_s_barrier();
    const u16* As = lds + (size_t)cur*BUFE;
    const u16* Bs = As + BM*32;
    bf16x8 af[MR], bf[NR];
    #pragma unroll
    for (int i=0;i<MR;i++){
      int r = wr*(MR*16) + i*16 + lane16;
      int g = lg ^ ((r>>1)&3);
      af[i] = *(const bf16x8*)(As + r*32 + g*8);
    }
    #pragma unroll
    for (int j=0;j<NR;j++){
      int r = wc*(NR*16) + j*16 + lane16;
      int g = lg ^ ((r>>1)&3);
      bf[j] = *(const bf16x8*)(Bs + r*32 + g*8);
    }
    int st = kt + NBUF-1;
    if (st < ntiles) STAGE(st, (cur==0)?(NBUF-1):(cur-1));
    __builtin_amdgcn_s_setprio(1);
    #pragma unroll
    for (int i=0;i<MR;i++)
      #pragma unroll
      for (int j=0;j<NR;j++)
        acc[i][j] = __builtin_amdgcn_mfma_f32_16x16x32_bf16(af[i], bf[j], acc[i][j], 0,0,0);
    __builtin_amdgcn_s_setprio(0);
    __builtin_amdgcn_sched_barrier(0);
    cur = (cur+1==NBUF)?0:(cur+1);
  }

  if constexpr (EPI==0){
    int region = (n0 < 3072) ? (int)(n0>>10) : 3;
    if (region<=1){
      u16* dst = (region==0)? qh : kh;
      float sc = (region==0)? 0.125f*1.44269504f : 1.0f;   // fold 1/8 and log2(e)
      int h = (int)((n0 & 1023)>>6) + wc;
      int d = lane16;
      #pragma unroll
      for (int i=0;i<MR;i++){
        #pragma unroll
        for (int r=0;r<4;r++){
          int row = (int)m0 + wr*(MR*16) + i*16 + lg*4 + r;
          int bb = row>>11, s = row&2047;
          float cs = tab[s*32+d], sn = tab[s*32+16+d];
          float x0 = acc[i][0][r], x1 = acc[i][1][r];
          size_t base = ((size_t)(bb*16+h)*SLEN + s)*64;
          dst[base+d]    = f2b((x0*cs - x1*sn)*sc);
          dst[base+16+d] = f2b((x1*cs + x0*sn)*sc);
          dst[base+32+d] = f2b(acc[i][2][r]*sc);
          dst[base+48+d] = f2b(acc[i][3][r]*sc);
        }
      }
    } else if (region==2){
      // direct vT write: vT (B,H,64,S), 4 consecutive s per lane packed as uint2
      #pragma unroll
      for (int j=0;j<NR;j++){
        int cv = (int)(n0-2048) + wc*(NR*16) + j*16 + lane16;
        int hh = cv>>6, dd = cv&63;
        #pragma unroll
        for (int i=0;i<MR;i++){
          int row0 = (int)m0 + wr*(MR*16) + i*16 + lg*4;
          int bb = row0>>11, s0 = row0&2047;
          union { u16 o[4]; uint2 v; } pk2;
          #pragma unroll
          for (int r=0;r<4;r++) pk2.o[r] = f2b(acc[i][j][r]);
          *(uint2*)(vt + ((size_t)(bb*16+hh)*64 + dd)*SLEN + s0) = pk2.v;
        }
      }
    } else {
      int fbase = (int)((n0-3072)>>1) + wc*(NR*8) + lane16;
      #pragma unroll
      for (int i=0;i<MR;i++)
        #pragma unroll
        for (int p=0;p<NR/2;p++){
          int col = 1024 + fbase + p*16;
          #pragma unroll
          for (int r=0;r<4;r++){
            int row = (int)m0 + wr*(MR*16) + i*16 + lg*4 + r;
            float fv = acc[i][2*p][r];
            float gv = acc[i][2*p+1][r];
            float tz = 0.7978845608f*(gv + 0.044715f*gv*gv*gv);
            float th = 1.f - 2.f/(__expf(2.f*tz)+1.f);
            afinal[(size_t)row*NFUSE + col] = f2b(fv * 0.5f*gv*(1.f+th));
          }
        }
    }
  } else {
    u16* pbs = pb + (size_t)blockIdx.z*MROWS*DMODEL;
    #pragma unroll
    for (int i=0;i<MR;i++)
      #pragma unroll
      for (int j=0;j<NR;j++){
        int col = (int)n0 + wc*(NR*16) + j*16 + lane16;
        #pragma unroll
        for (int r=0;r<4;r++){
          int row = (int)m0 + wr*(MR*16) + i*16 + lg*4 + r;
          pbs[(size_t)row*DMODEL + col] = f2b(acc[i][j][r]);
        }
      }
  }
}

// ---------------- reduce 2 bf16 partials + residual + bias ----------------
__global__ __launch_bounds__(256) void k_reduce(const u16* __restrict__ pb, const float* __restrict__ resid,
                                                const float* __restrict__ bias, float* __restrict__ out){
  size_t i8 = ((size_t)blockIdx.x*256 + threadIdx.x)*8;
  uint4 a0 = *(const uint4*)(pb + i8);
  uint4 a1 = *(const uint4*)(pb + (size_t)MROWS*DMODEL + i8);
  const u16* p0 = (const u16*)&a0;
  const u16* p1 = (const u16*)&a1;
  float4 r0 = *(const float4*)(resid + i8);
  float4 r1 = *(const float4*)(resid + i8 + 4);
  int bcol = (int)(i8 & 1023);
  float4 b0 = *(const float4*)(bias + bcol);
  float4 b1 = *(const float4*)(bias + bcol + 4);
  float4 o0, o1;
  const float* rr0 = (const float*)&r0; const float* bb0 = (const float*)&b0;
  const float* rr1 = (const float*)&r1; const float* bb1 = (const float*)&b1;
  float* oo0 = (float*)&o0; float* oo1 = (float*)&o1;
  #pragma unroll
  for (int k=0;k<4;k++){
    oo0[k] = b2f(p0[k]) + b2f(p1[k]) + rr0[k] + bb0[k];
    oo1[k] = b2f(p0[4+k]) + b2f(p1[4+k]) + rr1[k] + bb1[k];
  }
  *(float4*)(out + i8)     = o0;
  *(float4*)(out + i8 + 4) = o1;
}

// ---------------- flash attention: QBLK=128, full KV, fixed-shift softmax, sum-via-MFMA ----------------
#define M0SHIFT 20.0f
__global__ __launch_bounds__(256,3) void k_attn(const u16* __restrict__ qh, const u16* __restrict__ kh,
                                                const u16* __restrict__ vt, u16* __restrict__ afinal){
  __shared__ __attribute__((aligned(16))) u16 Klds[2][64*64];
  __shared__ __attribute__((aligned(16))) u16 Vlds[2][64*64];
  __shared__ __attribute__((aligned(16))) u16 Plds[4][32*72];
  // head->XCD swizzle: 512 blocks; XCD c hosts 4 heads, KV (2MB) stays L2-resident
  int p = (blockIdx.z*16 + blockIdx.y)*16 + blockIdx.x;   // 0..511
  int c = p&7, k = p>>3;                                  // k: 0..63
  int hb = c + 8*(k&3);                                   // 0..31 = b*16+h
  int qx = k>>2;                                          // 0..15
  int b = hb>>4, h = hb&15, q0 = qx*128;
  int t = threadIdx.x, w = t>>6, l = t&63;
  int lane16 = l&15, lg = l>>4;
  size_t hoff = (size_t)hb*SLEN*64;
  const u16* Qb = qh + hoff + (size_t)(q0 + w*32)*64;
  const u16* Kb = kh + hoff;
  const u16* Vb = vt + hoff;
  bf16x8 qf[2][2];
  #pragma unroll
  for (int mi=0;mi<2;mi++)
    #pragma unroll
    for (int ks=0;ks<2;ks++)
      qf[mi][ks] = *(const bf16x8*)(Qb + (size_t)(mi*16+lane16)*64 + ks*32 + lg*8);
  bf16x8 ones;
  #pragma unroll
  for (int i=0;i<8;i++) ones[i] = (__bf16)1.0f;
  f32x4 zero = {0.f,0.f,0.f,0.f};
  f32x4 acc[2][4];
  f32x4 lacc[2];
  #pragma unroll
  for (int mi=0;mi<2;mi++){
    lacc[mi] = zero;
    #pragma unroll
    for (int n=0;n<4;n++) acc[mi][n] = zero;
  }

  auto STAGE = [&](int buf, int kv0){
    #pragma unroll
    for (int r=0;r<2;r++){
      int cc = r*256 + t;
      int row = cc>>3;
      int g = (cc&7) ^ (row&7);
      gload16(Kb + (size_t)(kv0+row)*64 + g*8, (char*)Klds[buf] + r*4096 + w*1024);
      gload16(Vb + (size_t)row*SLEN + kv0 + g*8, (char*)Vlds[buf] + r*4096 + w*1024);
    }
  };

  STAGE(0, 0);
  __syncthreads();

  for (int tile=0; tile<32; ++tile){
    int cur = tile & 1;
    if (tile+1 < 32) STAGE(cur^1, (tile+1)*64);
    f32x4 sf[2][4];
    #pragma unroll
    for (int mi=0;mi<2;mi++)
      #pragma unroll
      for (int n=0;n<4;n++) sf[mi][n] = zero;
    __builtin_amdgcn_s_setprio(1);
    #pragma unroll
    for (int n=0;n<4;n++){
      #pragma unroll
      for (int ks=0;ks<2;ks++){
        int rk = n*16 + lane16;
        int g = (ks*4 + lg) ^ (rk&7);
        bf16x8 kf = *(const bf16x8*)(Klds[cur] + rk*64 + g*8);
        sf[0][n] = __builtin_amdgcn_mfma_f32_16x16x32_bf16(qf[0][ks], kf, sf[0][n], 0,0,0);
        sf[1][n] = __builtin_amdgcn_mfma_f32_16x16x32_bf16(qf[1][ks], kf, sf[1][n], 0,0,0);
      }
    }
    __builtin_amdgcn_s_setprio(0);
    #pragma unroll
    for (int mi=0;mi<2;mi++)
      #pragma unroll
      for (int jr=0;jr<4;jr++)
        #pragma unroll
        for (int n=0;n<4;n++){
          float pv = fexp2(sf[mi][n][jr] - M0SHIFT);
          u32 u; __builtin_memcpy(&u,&pv,4);
          Plds[w][(mi*16 + lg*4 + jr)*72 + n*16 + lane16] = (u16)(u>>16);
        }
    __builtin_amdgcn_s_setprio(1);
    #pragma unroll
    for (int ks=0;ks<2;ks++){
      bf16x8 vf[4];
      #pragma unroll
      for (int n=0;n<4;n++){
        int rv = n*16 + lane16;
        int g = (ks*4 + lg) ^ (rv&7);
        vf[n] = *(const bf16x8*)(Vlds[cur] + rv*64 + g*8);
      }
      #pragma unroll
      for (int mi=0;mi<2;mi++){
        bf16x8 pa = *(const bf16x8*)(&Plds[w][(mi*16 + lane16)*72 + ks*32 + lg*8]);
        #pragma unroll
        for (int n=0;n<4;n++)
          acc[mi][n] = __builtin_amdgcn_mfma_f32_16x16x32_bf16(pa, vf[n], acc[mi][n], 0,0,0);
        lacc[mi] = __builtin_amdgcn_mfma_f32_16x16x32_bf16(pa, ones, lacc[mi], 0,0,0);
      }
    }
    __builtin_amdgcn_s_setprio(0);
    __syncthreads();
  }
  // normalize and write bf16 directly to afinal cols 0..1023
  #pragma unroll
  for (int mi=0;mi<2;mi++){
    float inv[4];
    #pragma unroll
    for (int jr=0;jr<4;jr++) inv[jr] = 1.f/lacc[mi][jr];
    #pragma unroll
    for (int n=0;n<4;n++)
      #pragma unroll
      for (int jr=0;jr<4;jr++){
        int srow = q0 + w*32 + mi*16 + lg*4 + jr;
        int col = h*64 + n*16 + lane16;
        afinal[(size_t)(b*SLEN+srow)*NFUSE + col] = f2b(acc[mi][n][jr]*inv[jr]);
      }
  }
}

// ---------------- launch ----------------
extern "C" void kernel_launch(void* const* d_in, const int* in_sizes, int n_in,
                              void* d_out, int out_size, void* d_ws, size_t ws_size,
                              hipStream_t stream) {
  const float* inputs = (const float*)d_in[0];
  const float* te     = (const float*)d_in[1];
  const float* ln_w   = (const float*)d_in[2];
  const float* ln_b   = (const float*)d_in[3];
  const float* cond_w = (const float*)d_in[4];
  const float* cond_b = (const float*)d_in[5];
  const float* w_in   = (const float*)d_in[6];
  const float* w_attn = (const float*)d_in[7];
  const float* w_ff   = (const float*)d_in[8];
  const float* b_ff   = (const float*)d_in[9];
  float* out = (float*)d_out;

  char* ws = (char*)d_ws;
  size_t off = 0;
  auto alloc = [&](size_t n)->char*{ char* p = ws + off; off += (n + 255) & ~(size_t)255; return p; };
  u16*  w_inT    = (u16*)alloc((size_t)NPROJ*DMODEL*2);
  u16*  w_fusedT = (u16*)alloc((size_t)DMODEL*NFUSE*2);
  u16*  units    = (u16*)alloc((size_t)MROWS*DMODEL*2);
  u16*  qh       = (u16*)alloc((size_t)MROWS*DMODEL*2);
  u16*  kh       = (u16*)alloc((size_t)MROWS*DMODEL*2);
  u16*  vT       = (u16*)alloc((size_t)MROWS*DMODEL*2);
  u16*  afinal   = (u16*)alloc((size_t)MROWS*NFUSE*2);
  u16*  pb       = (u16*)alloc((size_t)2*MROWS*DMODEL*2);
  float* cond    = (float*)alloc(2*2048*4);
  float* ropetab = (float*)alloc((size_t)SLEN*32*4);
  (void)ws_size; (void)in_sizes; (void)n_in; (void)out_size;

  // weight prep + rope table + cond (one launch)
  k_prep<<<dim3(16384+128+16), 256, 0, stream>>>(w_in, w_attn, w_ff, te, cond_w, cond_b,
                                                 w_inT, w_fusedT, ropetab, cond);
  // LN + modulation
  k_ln<<<MROWS, 256, 0, stream>>>(inputs, ln_w, ln_b, cond, units);
  // fused qkv/ff projection: 256x256, NBUF=3, COLUMN-major decode (B=23MB large), fused epilogue
  k_gemm_pipe<256,256,2,4,3,2,0,1><<<dim3(NPROJ/256, MROWS/256), 512, 0, stream>>>(
      units, w_inT, DMODEL, DMODEL, DMODEL, ropetab, qh, kh, vT, afinal, nullptr);
  // attention -> afinal cols 0..1023 (QBLK=128, direct normalized write)
  k_attn<<<dim3(16, 16, 2), 256, 0, stream>>>(qh, kh, vT, afinal);
  // final fused GEMM: split-K x2 bf16 partials, ROW-major decode (B=10MB small, A-panels XCD-exclusive)
  k_gemm_pipe<128,128,2,2,3,3,1,0><<<dim3(DMODEL/128, MROWS/128, 2), 256, 0, stream>>>(
      afinal, w_fusedT, 2560, NFUSE, NFUSE, nullptr, nullptr, nullptr, nullptr, nullptr, pb);
  k_reduce<<<dim3(MROWS*DMODEL/2048), 256, 0, stream>>>(pb, inputs, b_ff, out);
}

// Round 15
// 271.531 us; speedup vs baseline: 1.1120x; 1.0391x over previous
//
#include <hip/hip_runtime.h>
#include <hip/hip_bf16.h>

typedef __attribute__((ext_vector_type(8))) __bf16 bf16x8;
typedef __attribute__((ext_vector_type(4))) float f32x4;
typedef unsigned short u16;
typedef unsigned int u32;

#define DMODEL 1024
#define SLEN   2048
#define NPROJ  11264
#define NFUSE  5120
#define MROWS  4096

__device__ __forceinline__ float b2f(u16 u){ u32 v=((u32)u)<<16; float f; __builtin_memcpy(&f,&v,4); return f; }
__device__ __forceinline__ u16 f2b(float f){ u32 u; __builtin_memcpy(&u,&f,4); u32 r=u+0x7fffu+((u>>16)&1u); return (u16)(r>>16); }
__device__ __forceinline__ float fexp2(float x){ return __builtin_amdgcn_exp2f(x); }

__device__ __forceinline__ void gload16(const void* g, void* l){
  __builtin_amdgcn_global_load_lds((__attribute__((address_space(1))) u32*)g,
                                   (__attribute__((address_space(3))) u32*)l, 16, 0, 0);
}

// ---------------- fused prep: 3 weight transposes + rope table + cond, one launch ----------------
__global__ __launch_bounds__(256) void k_prep(const float* __restrict__ w_in,
                                              const float* __restrict__ w_attn,
                                              const float* __restrict__ w_ff,
                                              const float* __restrict__ te,
                                              const float* __restrict__ cond_w,
                                              const float* __restrict__ cond_b,
                                              u16* __restrict__ w_inT,
                                              u16* __restrict__ w_fusedT,
                                              float* __restrict__ ropetab,
                                              float* __restrict__ cond){
  __shared__ float tile[32][33];
  __shared__ float sl[DMODEL];
  int bid = blockIdx.x;
  if (bid >= 16384){
    int xb = bid - 16384;
    if (xb < 128){
      int idx = xb*256 + threadIdx.x;
      int s = idx >> 4, i = idx & 15;
      float inv = powf(10000.f, -(float)i/16.f);
      float f = (float)s * inv;
      ropetab[s*32 + i]      = cosf(f);
      ropetab[s*32 + 16 + i] = sinf(f);
    } else {
      int cb2 = xb - 128;
      int b = cb2>>3, t = threadIdx.x;
      for (int i=t;i<DMODEL;i+=256){ float x = te[b*DMODEL+i]; sl[i] = x/(1.f+expf(-x)); }
      __syncthreads();
      int n = (cb2&7)*256 + t;
      float acc = 0.f;
      for (int k=0;k<DMODEL;k++) acc += sl[k]*cond_w[(size_t)k*2048 + n];
      cond[b*2048+n] = acc + cond_b[n];
    }
    return;
  }
  const float* src; u16* dst; int N, ldd, coloff, nx, remap, tix;
  if (bid < 11264){ tix=bid;       nx=352; src=w_in;   N=NPROJ;  dst=w_inT;    ldd=DMODEL; coloff=0;    remap=1; }
  else if (bid < 12288){ tix=bid-11264; nx=32; src=w_attn; N=DMODEL; dst=w_fusedT; ldd=NFUSE; coloff=0;    remap=0; }
  else {            tix=bid-12288; nx=32;  src=w_ff;   N=DMODEL; dst=w_fusedT; ldd=NFUSE;  coloff=1024; remap=0; }
  int n0 = (tix%nx)*32, k0 = (tix/nx)*32;
  int tx = threadIdx.x & 31, ty = threadIdx.x >> 5;
  int srccol;
  if (remap && (n0 + tx) >= 3072){
    int c = n0 + tx - 3072;
    int q = c >> 5, o = c & 31;
    srccol = (o < 16) ? (3072 + 16*q + o) : (7168 + 16*q + (o-16));
  } else srccol = n0 + tx;
  #pragma unroll
  for (int r=0;r<4;r++)
    tile[ty*4+r][tx] = src[(size_t)(k0+ty*4+r)*N + srccol];
  __syncthreads();
  // packed u32 stores: thread -> n row (t>>3), two k-words (t&7, +8)
  int nn = threadIdx.x >> 3;
  int kw8 = threadIdx.x & 7;
  u32* d32 = (u32*)(dst + (size_t)(n0+nn)*ldd + coloff + k0);
  #pragma unroll
  for (int hh=0; hh<2; hh++){
    int kw = kw8 + hh*8;
    u32 v = (u32)f2b(tile[2*kw][nn]) | ((u32)f2b(tile[2*kw+1][nn])<<16);
    d32[kw] = v;
  }
}

// ---------------- LayerNorm + modulation -> units bf16 ----------------
__global__ __launch_bounds__(256) void k_ln(const float* __restrict__ x, const float* __restrict__ lw,
                                            const float* __restrict__ lb, const float* __restrict__ cond,
                                            u16* __restrict__ units){
  int row = blockIdx.x; int b = row >> 11;
  int t = threadIdx.x;
  const float4 v = *(const float4*)(x + (size_t)row*DMODEL + t*4);
  float s = v.x+v.y+v.z+v.w;
  float q = v.x*v.x+v.y*v.y+v.z*v.z+v.w*v.w;
  #pragma unroll
  for (int off=32; off; off>>=1){ s += __shfl_xor(s,off); q += __shfl_xor(q,off); }
  __shared__ float red[8];
  int w = t>>6, l = t&63;
  if (l==0){ red[w]=s; red[4+w]=q; }
  __syncthreads();
  float S = red[0]+red[1]+red[2]+red[3];
  float Q = red[4]+red[5]+red[6]+red[7];
  float mu = S*(1.f/1024.f);
  float var = Q*(1.f/1024.f) - mu*mu;
  float rstd = rsqrtf(var + 1e-5f);
  int c0 = t*4;
  u16 o[4];
  const float* vf = (const float*)&v;
  #pragma unroll
  for (int i=0;i<4;i++){
    int c = c0+i;
    float nrm = (vf[i]-mu)*rstd*lw[c] + lb[c];
    float outv = (1.f + cond[b*2048 + c])*nrm + cond[b*2048 + 1024 + c];
    o[i] = f2b(outv);
  }
  u32 p0 = (u32)o[0] | ((u32)o[1]<<16);
  u32 p1 = (u32)o[2] | ((u32)o[3]<<16);
  uint2 pk; pk.x = p0; pk.y = p1;
  *(uint2*)(units + (size_t)row*DMODEL + c0) = pk;
}

// ================= pipelined GEMM: counted-vmcnt, raw barriers, NBUF LDS buffers =================
// CMAJ=1: column-major XCD decode (co-resident blocks share a B panel) — use when B is the LARGE operand.
// CMAJ=0: row-major (co-resident share an A panel) — use when B is small/L2-fittable.
// EPI 0: proj epilogue (rope/headsplit/vT-direct/ff-gate). EPI 1: split-K bf16 partials.
template<int BM,int BN,int WM,int WN,int NBUF,int MINW,int EPI,int CMAJ>
__global__ __launch_bounds__(WM*WN*64, MINW) void k_gemm_pipe(
    const u16* __restrict__ A, const u16* __restrict__ Bt, int K, int lda, int ldb,
    const float* __restrict__ tab, u16* __restrict__ qh, u16* __restrict__ kh,
    u16* __restrict__ vt, u16* __restrict__ afinal, u16* __restrict__ pb)
{
  constexpr int THREADS = WM*WN*64;
  constexpr int MR = BM/WM/16, NR = BN/WN/16;
  constexpr int BUFE = (BM+BN)*32;
  __shared__ __attribute__((aligned(16))) u16 lds[NBUF*BUFE];
  int t = threadIdx.x, w = t>>6, l = t&63;
  int wr = w/WN, wc = w%WN;
  int lane16 = l&15, lg = l>>4;

  int nbx = gridDim.x, nby = gridDim.y;
  int wg = blockIdx.y*nbx + blockIdx.x;
  int nwg = nbx*nby;
  int cpx = nwg>>3;
  int swz = (wg&7)*cpx + (wg>>3);
  int bx, by;
  if constexpr (CMAJ){ bx = swz / nby; by = swz - bx*nby; }
  else               { bx = swz % nbx; by = swz / nbx; }

  size_t m0 = (size_t)by*BM, n0 = (size_t)bx*BN;
  int koff = (EPI==1) ? blockIdx.z*2560 : 0;
  const u16* Ag = A + m0*lda + koff;
  const u16* Bg = Bt + n0*ldb + koff;

  f32x4 zero = {0.f,0.f,0.f,0.f};
  f32x4 acc[MR][NR];
  #pragma unroll
  for (int i=0;i<MR;i++)
    #pragma unroll
    for (int j=0;j<NR;j++) acc[i][j] = zero;

  const int ntiles = K/32;

  auto STAGE = [&](int tt, int buf){
    int k0 = tt*32;
    char* Ad = (char*)lds + (size_t)buf*(BUFE*2);
    char* Bd = Ad + BM*64;
    #pragma unroll
    for (int i=0;i<2;i++){
      int s = i*THREADS + t;
      int r = s>>2, g = s&3;
      int src = (g ^ ((r>>1)&3))*8;
      gload16(Ag + (size_t)r*lda + k0 + src, Ad + (i*THREADS + w*64)*16);
      gload16(Bg + (size_t)r*ldb + k0 + src, Bd + (i*THREADS + w*64)*16);
    }
  };

  #pragma unroll
  for (int p=0;p<NBUF-1;p++) STAGE(p, p);

  int cur = 0;
  for (int kt=0; kt<ntiles; ++kt){
    if constexpr (NBUF==2){
      asm volatile("s_waitcnt vmcnt(0)" ::: "memory");
    } else {
      int rem = ntiles-1-kt;
      if (rem>=1)      asm volatile("s_waitcnt vmcnt(4)" ::: "memory");
      else             asm volatile("s_waitcnt vmcnt(0)" ::: "memory");
    }
    __builtin_amdgcn_s_barrier();
    const u16* As = lds + (size_t)cur*BUFE;
    const u16* Bs = As + BM*32;
    bf16x8 af[MR], bf[NR];
    #pragma unroll
    for (int i=0;i<MR;i++){
      int r = wr*(MR*16) + i*16 + lane16;
      int g = lg ^ ((r>>1)&3);
      af[i] = *(const bf16x8*)(As + r*32 + g*8);
    }
    #pragma unroll
    for (int j=0;j<NR;j++){
      int r = wc*(NR*16) + j*16 + lane16;
      int g = lg ^ ((r>>1)&3);
      bf[j] = *(const bf16x8*)(Bs + r*32 + g*8);
    }
    int st = kt + NBUF-1;
    if (st < ntiles) STAGE(st, (cur==0)?(NBUF-1):(cur-1));
    __builtin_amdgcn_s_setprio(1);
    #pragma unroll
    for (int i=0;i<MR;i++)
      #pragma unroll
      for (int j=0;j<NR;j++)
        acc[i][j] = __builtin_amdgcn_mfma_f32_16x16x32_bf16(af[i], bf[j], acc[i][j], 0,0,0);
    __builtin_amdgcn_s_setprio(0);
    __builtin_amdgcn_sched_barrier(0);
    cur = (cur+1==NBUF)?0:(cur+1);
  }

  if constexpr (EPI==0){
    int region = (n0 < 3072) ? (int)(n0>>10) : 3;
    if (region<=1){
      u16* dst = (region==0)? qh : kh;
      float sc = (region==0)? 0.125f*1.44269504f : 1.0f;   // fold 1/8 and log2(e)
      int h = (int)((n0 & 1023)>>6) + wc;
      int d = lane16;
      #pragma unroll
      for (int i=0;i<MR;i++){
        #pragma unroll
        for (int r=0;r<4;r++){
          int row = (int)m0 + wr*(MR*16) + i*16 + lg*4 + r;
          int bb = row>>11, s = row&2047;
          float cs = tab[s*32+d], sn = tab[s*32+16+d];
          float x0 = acc[i][0][r], x1 = acc[i][1][r];
          size_t base = ((size_t)(bb*16+h)*SLEN + s)*64;
          dst[base+d]    = f2b((x0*cs - x1*sn)*sc);
          dst[base+16+d] = f2b((x1*cs + x0*sn)*sc);
          dst[base+32+d] = f2b(acc[i][2][r]*sc);
          dst[base+48+d] = f2b(acc[i][3][r]*sc);
        }
      }
    } else if (region==2){
      // direct vT write: vT (B,H,64,S), 4 consecutive s per lane packed as uint2
      #pragma unroll
      for (int j=0;j<NR;j++){
        int cv = (int)(n0-2048) + wc*(NR*16) + j*16 + lane16;
        int hh = cv>>6, dd = cv&63;
        #pragma unroll
        for (int i=0;i<MR;i++){
          int row0 = (int)m0 + wr*(MR*16) + i*16 + lg*4;
          int bb = row0>>11, s0 = row0&2047;
          union { u16 o[4]; uint2 v; } pk2;
          #pragma unroll
          for (int r=0;r<4;r++) pk2.o[r] = f2b(acc[i][j][r]);
          *(uint2*)(vt + ((size_t)(bb*16+hh)*64 + dd)*SLEN + s0) = pk2.v;
        }
      }
    } else {
      int fbase = (int)((n0-3072)>>1) + wc*(NR*8) + lane16;
      #pragma unroll
      for (int i=0;i<MR;i++)
        #pragma unroll
        for (int p=0;p<NR/2;p++){
          int col = 1024 + fbase + p*16;
          #pragma unroll
          for (int r=0;r<4;r++){
            int row = (int)m0 + wr*(MR*16) + i*16 + lg*4 + r;
            float fv = acc[i][2*p][r];
            float gv = acc[i][2*p+1][r];
            float tz = 0.7978845608f*(gv + 0.044715f*gv*gv*gv);
            float th = 1.f - 2.f/(__expf(2.f*tz)+1.f);
            afinal[(size_t)row*NFUSE + col] = f2b(fv * 0.5f*gv*(1.f+th));
          }
        }
    }
  } else {
    u16* pbs = pb + (size_t)blockIdx.z*MROWS*DMODEL;
    #pragma unroll
    for (int i=0;i<MR;i++)
      #pragma unroll
      for (int j=0;j<NR;j++){
        int col = (int)n0 + wc*(NR*16) + j*16 + lane16;
        #pragma unroll
        for (int r=0;r<4;r++){
          int row = (int)m0 + wr*(MR*16) + i*16 + lg*4 + r;
          pbs[(size_t)row*DMODEL + col] = f2b(acc[i][j][r]);
        }
      }
  }
}

// ---------------- reduce 2 bf16 partials + residual + bias ----------------
__global__ __launch_bounds__(256) void k_reduce(const u16* __restrict__ pb, const float* __restrict__ resid,
                                                const float* __restrict__ bias, float* __restrict__ out){
  size_t i8 = ((size_t)blockIdx.x*256 + threadIdx.x)*8;
  uint4 a0 = *(const uint4*)(pb + i8);
  uint4 a1 = *(const uint4*)(pb + (size_t)MROWS*DMODEL + i8);
  const u16* p0 = (const u16*)&a0;
  const u16* p1 = (const u16*)&a1;
  float4 r0 = *(const float4*)(resid + i8);
  float4 r1 = *(const float4*)(resid + i8 + 4);
  int bcol = (int)(i8 & 1023);
  float4 b0 = *(const float4*)(bias + bcol);
  float4 b1 = *(const float4*)(bias + bcol + 4);
  float4 o0, o1;
  const float* rr0 = (const float*)&r0; const float* bb0 = (const float*)&b0;
  const float* rr1 = (const float*)&r1; const float* bb1 = (const float*)&b1;
  float* oo0 = (float*)&o0; float* oo1 = (float*)&o1;
  #pragma unroll
  for (int k=0;k<4;k++){
    oo0[k] = b2f(p0[k]) + b2f(p1[k]) + rr0[k] + bb0[k];
    oo1[k] = b2f(p0[4+k]) + b2f(p1[4+k]) + rr1[k] + bb1[k];
  }
  *(float4*)(out + i8)     = o0;
  *(float4*)(out + i8 + 4) = o1;
}

// ---------------- flash attention: QBLK=128, full KV, fixed-shift softmax, sum-via-MFMA ----------------
#define M0SHIFT 20.0f
__global__ __launch_bounds__(256,3) void k_attn(const u16* __restrict__ qh, const u16* __restrict__ kh,
                                                const u16* __restrict__ vt, u16* __restrict__ afinal){
  __shared__ __attribute__((aligned(16))) u16 Klds[2][64*64];
  __shared__ __attribute__((aligned(16))) u16 Vlds[2][64*64];
  __shared__ __attribute__((aligned(16))) u16 Plds[4][32*72];
  // head->XCD swizzle: 512 blocks; XCD c hosts 4 heads, KV (2MB) stays L2-resident
  int p = (blockIdx.z*16 + blockIdx.y)*16 + blockIdx.x;   // 0..511
  int c = p&7, k = p>>3;                                  // k: 0..63
  int hb = c + 8*(k&3);                                   // 0..31 = b*16+h
  int qx = k>>2;                                          // 0..15
  int b = hb>>4, h = hb&15, q0 = qx*128;
  int t = threadIdx.x, w = t>>6, l = t&63;
  int lane16 = l&15, lg = l>>4;
  size_t hoff = (size_t)hb*SLEN*64;
  const u16* Qb = qh + hoff + (size_t)(q0 + w*32)*64;
  const u16* Kb = kh + hoff;
  const u16* Vb = vt + hoff;
  bf16x8 qf[2][2];
  #pragma unroll
  for (int mi=0;mi<2;mi++)
    #pragma unroll
    for (int ks=0;ks<2;ks++)
      qf[mi][ks] = *(const bf16x8*)(Qb + (size_t)(mi*16+lane16)*64 + ks*32 + lg*8);
  bf16x8 ones;
  #pragma unroll
  for (int i=0;i<8;i++) ones[i] = (__bf16)1.0f;
  f32x4 zero = {0.f,0.f,0.f,0.f};
  f32x4 acc[2][4];
  f32x4 lacc[2];
  #pragma unroll
  for (int mi=0;mi<2;mi++){
    lacc[mi] = zero;
    #pragma unroll
    for (int n=0;n<4;n++) acc[mi][n] = zero;
  }

  auto STAGE = [&](int buf, int kv0){
    #pragma unroll
    for (int r=0;r<2;r++){
      int cc = r*256 + t;
      int row = cc>>3;
      int g = (cc&7) ^ (row&7);
      gload16(Kb + (size_t)(kv0+row)*64 + g*8, (char*)Klds[buf] + r*4096 + w*1024);
      gload16(Vb + (size_t)row*SLEN + kv0 + g*8, (char*)Vlds[buf] + r*4096 + w*1024);
    }
  };

  STAGE(0, 0);
  __syncthreads();

  for (int tile=0; tile<32; ++tile){
    int cur = tile & 1;
    if (tile+1 < 32) STAGE(cur^1, (tile+1)*64);
    f32x4 sf[2][4];
    #pragma unroll
    for (int mi=0;mi<2;mi++)
      #pragma unroll
      for (int n=0;n<4;n++) sf[mi][n] = zero;
    __builtin_amdgcn_s_setprio(1);
    #pragma unroll
    for (int n=0;n<4;n++){
      #pragma unroll
      for (int ks=0;ks<2;ks++){
        int rk = n*16 + lane16;
        int g = (ks*4 + lg) ^ (rk&7);
        bf16x8 kf = *(const bf16x8*)(Klds[cur] + rk*64 + g*8);
        sf[0][n] = __builtin_amdgcn_mfma_f32_16x16x32_bf16(qf[0][ks], kf, sf[0][n], 0,0,0);
        sf[1][n] = __builtin_amdgcn_mfma_f32_16x16x32_bf16(qf[1][ks], kf, sf[1][n], 0,0,0);
      }
    }
    __builtin_amdgcn_s_setprio(0);
    #pragma unroll
    for (int mi=0;mi<2;mi++)
      #pragma unroll
      for (int jr=0;jr<4;jr++)
        #pragma unroll
        for (int n=0;n<4;n++){
          float pv = fexp2(sf[mi][n][jr] - M0SHIFT);
          u32 u; __builtin_memcpy(&u,&pv,4);
          Plds[w][(mi*16 + lg*4 + jr)*72 + n*16 + lane16] = (u16)(u>>16);
        }
    __builtin_amdgcn_s_setprio(1);
    #pragma unroll
    for (int ks=0;ks<2;ks++){
      bf16x8 vf[4];
      #pragma unroll
      for (int n=0;n<4;n++){
        int rv = n*16 + lane16;
        int g = (ks*4 + lg) ^ (rv&7);
        vf[n] = *(const bf16x8*)(Vlds[cur] + rv*64 + g*8);
      }
      #pragma unroll
      for (int mi=0;mi<2;mi++){
        bf16x8 pa = *(const bf16x8*)(&Plds[w][(mi*16 + lane16)*72 + ks*32 + lg*8]);
        #pragma unroll
        for (int n=0;n<4;n++)
          acc[mi][n] = __builtin_amdgcn_mfma_f32_16x16x32_bf16(pa, vf[n], acc[mi][n], 0,0,0);
        lacc[mi] = __builtin_amdgcn_mfma_f32_16x16x32_bf16(pa, ones, lacc[mi], 0,0,0);
      }
    }
    __builtin_amdgcn_s_setprio(0);
    __syncthreads();
  }
  // normalize and write bf16 directly to afinal cols 0..1023
  #pragma unroll
  for (int mi=0;mi<2;mi++){
    float inv[4];
    #pragma unroll
    for (int jr=0;jr<4;jr++) inv[jr] = 1.f/lacc[mi][jr];
    #pragma unroll
    for (int n=0;n<4;n++)
      #pragma unroll
      for (int jr=0;jr<4;jr++){
        int srow = q0 + w*32 + mi*16 + lg*4 + jr;
        int col = h*64 + n*16 + lane16;
        afinal[(size_t)(b*SLEN+srow)*NFUSE + col] = f2b(acc[mi][n][jr]*inv[jr]);
      }
  }
}

// ---------------- launch ----------------
extern "C" void kernel_launch(void* const* d_in, const int* in_sizes, int n_in,
                              void* d_out, int out_size, void* d_ws, size_t ws_size,
                              hipStream_t stream) {
  const float* inputs = (const float*)d_in[0];
  const float* te     = (const float*)d_in[1];
  const float* ln_w   = (const float*)d_in[2];
  const float* ln_b   = (const float*)d_in[3];
  const float* cond_w = (const float*)d_in[4];
  const float* cond_b = (const float*)d_in[5];
  const float* w_in   = (const float*)d_in[6];
  const float* w_attn = (const float*)d_in[7];
  const float* w_ff   = (const float*)d_in[8];
  const float* b_ff   = (const float*)d_in[9];
  float* out = (float*)d_out;

  char* ws = (char*)d_ws;
  size_t off = 0;
  auto alloc = [&](size_t n)->char*{ char* p = ws + off; off += (n + 255) & ~(size_t)255; return p; };
  u16*  w_inT    = (u16*)alloc((size_t)NPROJ*DMODEL*2);
  u16*  w_fusedT = (u16*)alloc((size_t)DMODEL*NFUSE*2);
  u16*  units    = (u16*)alloc((size_t)MROWS*DMODEL*2);
  u16*  qh       = (u16*)alloc((size_t)MROWS*DMODEL*2);
  u16*  kh       = (u16*)alloc((size_t)MROWS*DMODEL*2);
  u16*  vT       = (u16*)alloc((size_t)MROWS*DMODEL*2);
  u16*  afinal   = (u16*)alloc((size_t)MROWS*NFUSE*2);
  u16*  pb       = (u16*)alloc((size_t)2*MROWS*DMODEL*2);
  float* cond    = (float*)alloc(2*2048*4);
  float* ropetab = (float*)alloc((size_t)SLEN*32*4);
  (void)ws_size; (void)in_sizes; (void)n_in; (void)out_size;

  // weight prep + rope table + cond (one launch)
  k_prep<<<dim3(16384+128+16), 256, 0, stream>>>(w_in, w_attn, w_ff, te, cond_w, cond_b,
                                                 w_inT, w_fusedT, ropetab, cond);
  // LN + modulation
  k_ln<<<MROWS, 256, 0, stream>>>(inputs, ln_w, ln_b, cond, units);
  // fused qkv/ff projection: 256x256, NBUF=2 (64KB LDS -> 2 blocks/CU), column decode, fused epilogue
  k_gemm_pipe<256,256,2,4,2,2,0,1><<<dim3(NPROJ/256, MROWS/256), 512, 0, stream>>>(
      units, w_inT, DMODEL, DMODEL, DMODEL, ropetab, qh, kh, vT, afinal, nullptr);
  // attention -> afinal cols 0..1023 (QBLK=128, direct normalized write)
  k_attn<<<dim3(16, 16, 2), 256, 0, stream>>>(qh, kh, vT, afinal);
  // final fused GEMM: split-K x2 bf16 partials, ROW-major decode (B small, A-panels XCD-exclusive)
  k_gemm_pipe<128,128,2,2,3,3,1,0><<<dim3(DMODEL/128, MROWS/128, 2), 256, 0, stream>>>(
      afinal, w_fusedT, 2560, NFUSE, NFUSE, nullptr, nullptr, nullptr, nullptr, nullptr, pb);
  k_reduce<<<dim3(MROWS*DMODEL/2048), 256, 0, stream>>>(pb, inputs, b_ff, out);
}